// Round 17
// baseline (227.490 us; speedup 1.0000x reference)
//
#include <hip/hip_runtime.h>
#include <hip/hip_bf16.h>
#include <cstdint>

typedef unsigned int u32;
typedef unsigned long long u64;

#define ANUM 131072
#define BATCH 4
#define PRE 3000
#define CAP 8192       /* candidate slack: threshold is bin-floor (coarse), rank fixes order */
#define NW 47          /* ceil(3000/64) */
#define MROW 48        /* padded u64 words per mask row */
#define MAXOUT 1000
#define NBUCK 64       /* candidate buckets per batch */
#define BCAP 256       /* slots per bucket (lambda~69, overflow impossible) */
#define NSUB 16        /* histogram sub-blocks per batch */
#define NSPLIT 8       /* comparand splits in k_rank_part */

/* ---- workspace layout (bytes) ---- */
#define OFF_PART   0ul                 /* u32[B][4096][NSUB] = 1MB */
#define OFF_CAND   0ul                 /* u64[B][NBUCK][BCAP] = 512KB (aliases part) */
#define OFF_DIAG   1048576ul           /* u64[B][NW][64] = 96256 */
#define OFF_DENSE  1179648ul           /* u64[B][CAP] = 262144 -> ends 1441792 */
#define OFF_RANKB  1441792ul           /* u32[B][CAP] = 131072 -> ends 1572864 */
#define OFF_INFO   2097152ul           /* u32[256]: [8..11]=T32 [16..19]=keptcnt [20..23]=total */
#define OFF_ROWNZ  2098176ul           /* u64[B][NW]=1504 -> pad 2KB (zeroed by k_h12 blk0) */
#define OFF_DONEC  2099712ul           /* u32[4] compact done counters (in rownz pad) */
#define OFF_DONER  2099728ul           /* u32[4] rank_part done counters (in rownz pad) */
#define OFF_BCNT   2100224ul           /* u32[B*NBUCK*16] = 16KB (zeroed by k_h12 blk0) */
#define OFF_SCORE  2164608ul           /* f32[B][PRE] */
#define OFF_BOXES  2212608ul           /* f32[B][PRE][6] */
#define OFF_MASKS  2500608ul           /* u64[B][PRE][MROW] = 4608000 */
#define OFF_KEPT   7108608ul           /* u32[B][PRE] -> end 7156608 */
#define ZERO_WORDS 4608                /* (rownz pad 2KB + bcnt 16KB) / 4 — covers done ctrs */

__device__ __forceinline__ u32 score_key(float f) {
  u32 u = __float_as_uint(f);
  return (u & 0x80000000u) ? ~u : (u | 0x80000000u);
}

/* ---------- 1. 12-bit LDS-privatized histogram + zero-init of atomics ---------- */
__global__ __launch_bounds__(256) void k_h12(const float* __restrict__ scores,
                                             u32* __restrict__ part,
                                             u32* __restrict__ zr /* rownz+done+bcnt */) {
  __shared__ u32 lh[4096];
  int b = blockIdx.x >> 4, sub = blockIdx.x & (NSUB - 1);
  int tid = threadIdx.x;
  if (blockIdx.x == 0) {                               /* zero rownz+done+bcnt (18KB) */
#pragma unroll
    for (int i = 0; i < ZERO_WORDS / 256; ++i) zr[i * 256 + tid] = 0u;
  }
  for (int i = tid; i < 4096; i += 256) lh[i] = 0;
  __syncthreads();
  const float4* src = (const float4*)(scores + (size_t)b * ANUM) + (size_t)sub * 2048;
#pragma unroll
  for (int it = 0; it < 8; ++it) {
    float4 v = src[it * 256 + tid];
    atomicAdd(&lh[score_key(v.x) >> 20], 1u);
    atomicAdd(&lh[score_key(v.y) >> 20], 1u);
    atomicAdd(&lh[score_key(v.z) >> 20], 1u);
    atomicAdd(&lh[score_key(v.w) >> 20], 1u);
  }
  __syncthreads();
  u32* P = part + (size_t)b * 4096 * NSUB;
  for (int i = tid; i < 4096; i += 256) P[i * NSUB + sub] = lh[i];
}

/* ---------- 2. find 12-bit bin crossing rank 3000 -> coarse threshold T ---------- */
__global__ void k_sel12(const u32* __restrict__ part, u32* __restrict__ info) {
  int b = blockIdx.x, tid = threadIdx.x;              /* 256 threads */
  __shared__ u32 strip[256];
  const u32* P = part + (size_t)b * 4096 * NSUB;
  u32 s = 0;
  for (int j = 0; j < 16; ++j) {
    int bin = 4095 - (tid * 16 + j);
    u32 acc = 0;
#pragma unroll
    for (int sub = 0; sub < NSUB; ++sub) acc += P[bin * NSUB + sub];
    s += acc;
  }
  strip[tid] = s;
  __syncthreads();
  if (tid == 0) {
    u32 c = 0; int ts = 0; u32 cb = 0;
    for (int t = 0; t < 256; ++t) {
      if (c + strip[t] >= PRE) { ts = t; cb = c; break; }
      c += strip[t];
    }
    u32 cc = cb; int b12 = 0;
    for (int r = ts * 16; r < 4096; ++r) {
      int bin = 4095 - r;
      u32 acc = 0;
      for (int sub = 0; sub < NSUB; ++sub) acc += P[bin * NSUB + sub];
      if (cc + acc >= PRE) { b12 = bin; break; }
      cc += acc;
    }
    info[8 + b] = ((u32)b12) << 20;                    /* coarse threshold T32 */
  }
}

/* ---------- 3. compact (float4) + last-block-per-batch gather tail ---------- */
__global__ __launch_bounds__(256) void k_compact(const float4* __restrict__ scores4,
                                                 const u32* __restrict__ info,
                                                 u32* __restrict__ bcnt,
                                                 u64* __restrict__ cand,
                                                 u64* __restrict__ dense,
                                                 u32* __restrict__ rankbuf,
                                                 u32* __restrict__ donec,
                                                 u32* __restrict__ infow) {
  int tid = threadIdx.x;
  int t = blockIdx.x * 256 + tid;                      /* 0 .. B*ANUM/4-1 */
  int b = t >> 15;                                     /* 128 blocks/batch, uniform */
  int e0 = (t & 32767) * 4;
  int bucket = (blockIdx.x >> 1) & (NBUCK - 1);        /* 2 blocks/bucket */
  u32 T = info[8 + b];
  float4 v = scores4[t];
  float fv[4] = {v.x, v.y, v.z, v.w};
#pragma unroll
  for (int q = 0; q < 4; ++q) {
    u32 key = score_key(fv[q]);
    if (key >= T) {
      u32 pos = atomicAdd(&bcnt[(u32)((b << 6) + bucket) * 16u], 1u);
      if (pos < BCAP)
        cand[(size_t)((b << 6) + bucket) * BCAP + pos] =
            ((u64)key << 32) | (u32)(~(u32)(e0 + q));
    }
  }
  /* ---- release + last-block check ---- */
  __threadfence();
  __syncthreads();
  __shared__ u32 isLast;
  if (tid == 0) isLast = (atomicAdd(&donec[b], 1u) == 127u) ? 1u : 0u;
  __syncthreads();
  if (!isLast) return;
  __threadfence();                                     /* acquire */

  /* ---- gather tail for batch b (256 threads) ---- */
  __shared__ u32 pref[NBUCK + 1];
  if (tid < NBUCK) {                                   /* wave 0 scan */
    u32 c = bcnt[(u32)((b << 6) + tid) * 16u];
    if (c > BCAP) c = BCAP;
    u32 inc = c;
#pragma unroll
    for (int d = 1; d < 64; d <<= 1) {
      u32 vv = __shfl_up(inc, d);
      if (tid >= d) inc += vv;
    }
    pref[tid + 1] = inc;
    if (tid == 0) pref[0] = 0;
  }
  __syncthreads();
  u32 total = pref[NBUCK]; if (total > CAP) total = CAP;
  if (tid == 0) infow[20 + b] = total;
  for (int i = tid; i < CAP; i += 256) {
    rankbuf[(size_t)b * CAP + i] = 0u;
    dense[(size_t)b * CAP + i] = 0ull;
  }
  __syncthreads();
  for (int j = tid; j < NBUCK * BCAP; j += 256) {
    int bk = j >> 8, sl = j & (BCAP - 1);
    u32 c = pref[bk + 1] - pref[bk];
    u32 pos = pref[bk] + (u32)sl;
    if ((u32)sl < c && pos < CAP)
      dense[(size_t)b * CAP + pos] = cand[(size_t)((b << 6) + bk) * BCAP + sl];
  }
}

/* ---------- 4. partial rank + last-block-per-batch scatter/regress tail ---------- */
__global__ __launch_bounds__(256) void k_rank_part(const u64* __restrict__ dense,
                                                   const u32* __restrict__ info,
                                                   u32* __restrict__ rankbuf,
                                                   u32* __restrict__ doner,
                                                   const float* __restrict__ anchors,
                                                   const float* __restrict__ deltas,
                                                   float* __restrict__ scoresel,
                                                   float* __restrict__ boxes) {
  int b = blockIdx.z;                                  /* 32*8 = 256 blocks/batch */
  int tid = threadIdx.x;
  int i = blockIdx.x * 256 + tid;
  int n = (int)info[20 + b];
  const u64* Kp = dense + (size_t)b * CAP;

  if (blockIdx.x * 256 < n) {                          /* key block has live keys */
    int ntile = (n + 63) >> 6;
    int tper = (ntile + NSPLIT - 1) / NSPLIT;
    int t0 = blockIdx.y * tper;
    if (t0 < ntile) {
      int t1 = t0 + tper; if (t1 > ntile) t1 = ntile;
      u64 mykey = Kp[i];
      int lane = tid & 63;
      int rank = 0;
      for (int t = t0; t < t1; ++t) {
        u64 kv = Kp[t * 64 + lane];                    /* coalesced per-lane tile */
        u32 klo = (u32)kv, khi = (u32)(kv >> 32);
#pragma unroll
        for (int l = 0; l < 64; ++l) {
          u32 slo = (u32)__builtin_amdgcn_readlane((int)klo, l);
          u32 shi = (u32)__builtin_amdgcn_readlane((int)khi, l);
          u64 sk = ((u64)shi << 32) | (u64)slo;
          rank += (sk > mykey) ? 1 : 0;
        }
      }
      if (rank) atomicAdd(&rankbuf[(size_t)b * CAP + i], (u32)rank);
    }
  }
  /* ---- release + last-block check ---- */
  __threadfence();
  __syncthreads();
  __shared__ u32 isLast;
  if (tid == 0) isLast = (atomicAdd(&doner[b], 1u) == 255u) ? 1u : 0u;
  __syncthreads();
  if (!isLast) return;
  __threadfence();                                     /* acquire */

  /* ---- scatter + regress tail for batch b (256 threads) ---- */
  for (int k = tid; k < n; k += 256) {
    u64 mykey = Kp[k];
    u32 rank = rankbuf[(size_t)b * CAP + k];
    if ((u32)mykey == 0u || rank >= PRE) continue;
    u32 key = (u32)(mykey >> 32);
    u32 e = ~((u32)mykey);
    u32 u = (key & 0x80000000u) ? (key ^ 0x80000000u) : ~key;
    scoresel[b * PRE + rank] = __uint_as_float(u);
    const float* an = anchors + (size_t)e * 6;
    const float* de = deltas + ((size_t)b * ANUM + e) * 6;
    float* ob = boxes + ((size_t)b * PRE + rank) * 6;
#pragma unroll
    for (int d = 0; d < 3; ++d) {
      float lo = an[d], hi = an[3 + d];
      float dims = __fsub_rn(hi, lo);
      float ctr = __fadd_rn(lo, __fmul_rn(0.5f, dims));
      ctr = __fadd_rn(ctr, __fmul_rn(de[d], dims));
      float nd = __fmul_rn(dims, expf(de[3 + d]));
      float h = __fmul_rn(0.5f, nd);
      ob[d] = __fsub_rn(ctr, h);
      ob[3 + d] = __fadd_rn(ctr, h);
    }
  }
}

/* ---------- 5. suppression bitmask matrix — UPPER TRIANGLE ONLY ---------- */
__global__ void k_mask(const float* __restrict__ boxes, u64* __restrict__ masks,
                       u64* __restrict__ diag, u64* __restrict__ rownz) {
  int jblk = blockIdx.x, iblk = blockIdx.y, b = blockIdx.z;
  if (jblk < iblk) return;                             /* uniform whole-block exit */
  int tid = threadIdx.x;                                /* 64 */
  __shared__ float cb[64][7];
  int j0 = jblk * 64;
  {
    int jj = j0 + tid; if (jj > PRE - 1) jj = PRE - 1;
    const float* src = boxes + ((size_t)b * PRE + jj) * 6;
#pragma unroll
    for (int d = 0; d < 6; ++d) cb[tid][d] = src[d];
    float dx = fmaxf(__fsub_rn(cb[tid][3], cb[tid][0]), 0.0f);
    float dy = fmaxf(__fsub_rn(cb[tid][4], cb[tid][1]), 0.0f);
    float dz = fmaxf(__fsub_rn(cb[tid][5], cb[tid][2]), 0.0f);
    cb[tid][6] = __fmul_rn(__fmul_rn(dx, dy), dz);
  }
  __syncthreads();
  int i = iblk * 64 + tid;
  if (i >= PRE) return;
  u64 bits = 0;
  if (j0 + 63 > i) {
    const float* rb = boxes + ((size_t)b * PRE + i) * 6;
    float l0 = rb[0], l1 = rb[1], l2 = rb[2], h0 = rb[3], h1 = rb[4], h2 = rb[5];
    float dx = fmaxf(__fsub_rn(h0, l0), 0.0f);
    float dy = fmaxf(__fsub_rn(h1, l1), 0.0f);
    float dz = fmaxf(__fsub_rn(h2, l2), 0.0f);
    float vi = __fmul_rn(__fmul_rn(dx, dy), dz);
    for (int c = 0; c < 64; ++c) {
      int j = j0 + c;
      if (j > i && j < PRE) {
        float ix = fmaxf(__fsub_rn(fminf(h0, cb[c][3]), fmaxf(l0, cb[c][0])), 0.0f);
        float iy = fmaxf(__fsub_rn(fminf(h1, cb[c][4]), fmaxf(l1, cb[c][1])), 0.0f);
        float iz = fmaxf(__fsub_rn(fminf(h2, cb[c][5]), fmaxf(l2, cb[c][2])), 0.0f);
        float iv = __fmul_rn(__fmul_rn(ix, iy), iz);
        float un = fmaxf(__fsub_rn(__fadd_rn(vi, cb[c][6]), iv), 1e-8f);
        float iou = __fdiv_rn(iv, un);
        if (iou > 0.7f) bits |= (1ull << c);
      }
    }
  }
  masks[((size_t)b * PRE + i) * MROW + jblk] = bits;
  if (iblk == jblk) diag[((size_t)b * NW + jblk) * 64 + tid] = bits;
  u64 bal = __ballot(bits != 0ull);
  if (tid == 0 && bal) atomicOr(&rownz[b * NW + iblk], bal);
}

/* ---------- 6. sparse single-wave NMS scan + output-assembly tail ---------- */
__global__ __launch_bounds__(64) void k_scan(const u64* __restrict__ masks,
                                             const u64* __restrict__ diag,
                                             const u64* __restrict__ rownz,
                                             u32* __restrict__ kept,
                                             u32* __restrict__ info,
                                             const float* __restrict__ boxes,
                                             const float* __restrict__ scoresel,
                                             float* __restrict__ out) {
  int b = blockIdx.x;
  int lane = threadIdx.x;                               /* 64 */
  const u64* Mb = masks + (size_t)b * PRE * MROW;
  const u64* Db = diag + (size_t)b * NW * 64;
  const u64* Nb = rownz + b * NW;
  int wl = lane < NW ? lane : NW - 1;
  u64 rem = 0;
  int cnt = 0;

  u64 dcur = Db[lane];
  u64 nzcur = Nb[0];

  for (int c = 0; c < NW; ++c) {
    int base = c * 64;
    int nrow = (base + 64 <= PRE) ? 64 : (PRE - base);

    u64 dn = (c + 1 < NW) ? Db[(size_t)(c + 1) * 64 + lane] : 0ull;
    u64 nzn = (c + 1 < NW) ? Nb[c + 1] : 0ull;

    u32 rlo = __shfl((u32)rem, c);
    u32 rhi = __shfl((u32)(rem >> 32), c);
    u64 pending = ~(((u64)rhi << 32) | (u64)rlo);
    if (nrow < 64) pending &= ((1ull << nrow) - 1ull);

    u64 Z = __ballot(dcur != 0ull);
    u64 chain = pending & Z;
    while (chain) {
      int k = __builtin_ctzll(chain);
      u32 rl = (u32)__builtin_amdgcn_readlane((int)(u32)dcur, k);
      u32 rh = (u32)__builtin_amdgcn_readlane((int)(u32)(dcur >> 32), k);
      u64 rw = ((u64)rh << 32) | (u64)rl;
      pending &= ~rw;
      chain &= pending;
      chain &= ~(1ull << k);
    }
    u64 keep = pending;

    u64 ltmask = (lane == 0) ? 0ull : (~0ull >> (64 - lane));
    int pos = __popcll(keep & ltmask);
    if ((keep >> lane) & 1ull) kept[b * PRE + cnt + pos] = (u32)(base + lane);
    cnt += (int)__popcll(keep);

    if (cnt >= MAXOUT) break;

    u64 nz = keep & nzcur;
    while (nz) {
      int rks[8]; int m = 0; int rr = base;
#pragma unroll
      for (int s = 0; s < 8; ++s) {
        if (nz) { rr = base + __builtin_ctzll(nz); nz &= nz - 1; ++m; }
        rks[s] = rr;
      }
      u64 v[8];
#pragma unroll
      for (int s = 0; s < 8; ++s) v[s] = Mb[(size_t)rks[s] * MROW + wl];
      u64 acc = 0;
#pragma unroll
      for (int s = 0; s < 8; ++s) acc |= (s < m) ? v[s] : 0ull;
      rem |= acc;
    }

    dcur = dn;
    nzcur = nzn;
  }
  if (lane == 0) info[16 + b] = (u32)cnt;
  __syncthreads();                                     /* drain kept[] stores */

  /* ---- output assembly tail (same wave) ---- */
  int cc = cnt > MAXOUT ? MAXOUT : cnt;
  for (int k = lane; k < MAXOUT; k += 64) {
    float pr[6] = {0.f, 0.f, 0.f, 0.f, 0.f, 0.f};
    float s = 0.f, vfl = 0.f;
    if (k < cc) {
      u32 i = kept[b * PRE + k];
      const float* bx = boxes + ((size_t)b * PRE + i) * 6;
#pragma unroll
      for (int d = 0; d < 6; ++d) pr[d] = bx[d];
      s = scoresel[b * PRE + i];
      vfl = 1.f;
    }
    float* pp = out + ((size_t)(b * MAXOUT + k)) * 6;
#pragma unroll
    for (int d = 0; d < 6; ++d) pp[d] = pr[d];
    out[BATCH * MAXOUT * 6 + b * MAXOUT + k] = s;
    out[BATCH * MAXOUT * 7 + b * MAXOUT + k] = (float)b;
    out[BATCH * MAXOUT * 8 + b * MAXOUT + k] = vfl;
  }
}

extern "C" void kernel_launch(void* const* d_in, const int* in_sizes, int n_in,
                              void* d_out, int out_size, void* d_ws, size_t ws_size,
                              hipStream_t stream) {
  const float* anchors = (const float*)d_in[0];
  const float* scores  = (const float*)d_in[1];
  const float* deltas  = (const float*)d_in[2];
  float* out = (float*)d_out;

  char* w = (char*)d_ws;
  u32* part    = (u32*)(w + OFF_PART);
  u64* cand    = (u64*)(w + OFF_CAND);
  u64* diag    = (u64*)(w + OFF_DIAG);
  u64* dense   = (u64*)(w + OFF_DENSE);
  u32* rankbuf = (u32*)(w + OFF_RANKB);
  u32* info    = (u32*)(w + OFF_INFO);
  u64* rownz   = (u64*)(w + OFF_ROWNZ);
  u32* donec   = (u32*)(w + OFF_DONEC);
  u32* doner   = (u32*)(w + OFF_DONER);
  u32* bcnt    = (u32*)(w + OFF_BCNT);
  float* scoresel = (float*)(w + OFF_SCORE);
  float* boxes = (float*)(w + OFF_BOXES);
  u64* masks   = (u64*)(w + OFF_MASKS);
  u32* kept    = (u32*)(w + OFF_KEPT);

  k_h12<<<BATCH * NSUB, 256, 0, stream>>>(scores, part, (u32*)(w + OFF_ROWNZ));
  k_sel12<<<BATCH, 256, 0, stream>>>(part, info);
  k_compact<<<BATCH * ANUM / 4 / 256, 256, 0, stream>>>((const float4*)scores, info, bcnt,
                                                        cand, dense, rankbuf, donec, info);
  k_rank_part<<<dim3(CAP / 256, NSPLIT, BATCH), 256, 0, stream>>>(dense, info, rankbuf, doner,
                                                                  anchors, deltas, scoresel,
                                                                  boxes);
  k_mask<<<dim3(NW, NW, BATCH), 64, 0, stream>>>(boxes, masks, diag, rownz);
  k_scan<<<BATCH, 64, 0, stream>>>(masks, diag, rownz, kept, info, boxes, scoresel, out);
}

// Round 18
// 104.700 us; speedup vs baseline: 2.1728x; 2.1728x over previous
//
#include <hip/hip_runtime.h>
#include <hip/hip_bf16.h>
#include <cstdint>

typedef unsigned int u32;
typedef unsigned long long u64;

#define ANUM 131072
#define BATCH 4
#define PRE 3000
#define CAP 8192       /* candidate slack: threshold is bin-floor (coarse), rank fixes order */
#define NW 47          /* ceil(3000/64) */
#define MROW 48        /* padded u64 words per mask row */
#define MAXOUT 1000
#define NBUCK 64       /* candidate buckets per batch */
#define BCAP 256       /* slots per bucket (lambda~69, overflow impossible) */
#define NSUB 16        /* histogram sub-blocks per batch */
#define NSPLIT 8       /* comparand splits in k_rank_part */

/* ---- workspace layout (bytes) ---- */
#define OFF_PART   0ul                 /* u32[B][4096][NSUB] = 1MB */
#define OFF_CAND   0ul                 /* u64[B][NBUCK][BCAP] = 512KB (aliases part) */
#define OFF_DIAG   1048576ul           /* u64[B][NW][64] = 96256 */
#define OFF_DENSE  1179648ul           /* u64[B][CAP] = 262144 -> ends 1441792 */
#define OFF_RANKB  1441792ul           /* u32[B][CAP] = 131072 -> ends 1572864 */
#define OFF_INFO   2097152ul           /* u32[256]: [8..11]=T32 [16..19]=keptcnt [20..23]=total */
#define OFF_ROWNZ  2098176ul           /* u64[B][NW]=1504 -> pad 2KB (zeroed by k_h12 blk0) */
#define OFF_BCNT   2100224ul           /* u32[B*NBUCK*16] = 16KB (zeroed by k_h12 blk0) */
#define OFF_SCORE  2164608ul           /* f32[B][PRE] */
#define OFF_BOXES  2212608ul           /* f32[B][PRE][6] */
#define OFF_MASKS  2500608ul           /* u64[B][PRE][MROW] = 4608000 */
#define OFF_KEPT   7108608ul           /* u32[B][PRE] -> end 7156608 */
#define ZERO_WORDS 4608                /* (rownz pad 2KB + bcnt 16KB) / 4 */

__device__ __forceinline__ u32 score_key(float f) {
  u32 u = __float_as_uint(f);
  return (u & 0x80000000u) ? ~u : (u | 0x80000000u);
}

/* ---------- 1. 12-bit LDS-privatized histogram + zero-init of atomics ---------- */
__global__ __launch_bounds__(256) void k_h12(const float* __restrict__ scores,
                                             u32* __restrict__ part,
                                             u32* __restrict__ zr /* rownz+bcnt */) {
  __shared__ u32 lh[4096];
  int b = blockIdx.x >> 4, sub = blockIdx.x & (NSUB - 1);
  int tid = threadIdx.x;
  if (blockIdx.x == 0) {                               /* zero rownz+bcnt (18KB) */
#pragma unroll
    for (int i = 0; i < ZERO_WORDS / 256; ++i) zr[i * 256 + tid] = 0u;
  }
  for (int i = tid; i < 4096; i += 256) lh[i] = 0;
  __syncthreads();
  const float4* src = (const float4*)(scores + (size_t)b * ANUM) + (size_t)sub * 2048;
#pragma unroll
  for (int it = 0; it < 8; ++it) {
    float4 v = src[it * 256 + tid];
    atomicAdd(&lh[score_key(v.x) >> 20], 1u);
    atomicAdd(&lh[score_key(v.y) >> 20], 1u);
    atomicAdd(&lh[score_key(v.z) >> 20], 1u);
    atomicAdd(&lh[score_key(v.w) >> 20], 1u);
  }
  __syncthreads();
  u32* P = part + (size_t)b * 4096 * NSUB;
  for (int i = tid; i < 4096; i += 256) P[i * NSUB + sub] = lh[i];
}

/* ---------- 2. find 12-bit bin crossing rank 3000 -> coarse threshold T ---------- */
__global__ void k_sel12(const u32* __restrict__ part, u32* __restrict__ info) {
  int b = blockIdx.x, tid = threadIdx.x;              /* 256 threads */
  __shared__ u32 strip[256];
  const u32* P = part + (size_t)b * 4096 * NSUB;
  u32 s = 0;
  for (int j = 0; j < 16; ++j) {
    int bin = 4095 - (tid * 16 + j);
    u32 acc = 0;
#pragma unroll
    for (int sub = 0; sub < NSUB; ++sub) acc += P[bin * NSUB + sub];
    s += acc;
  }
  strip[tid] = s;
  __syncthreads();
  if (tid == 0) {
    u32 c = 0; int ts = 0; u32 cb = 0;
    for (int t = 0; t < 256; ++t) {
      if (c + strip[t] >= PRE) { ts = t; cb = c; break; }
      c += strip[t];
    }
    u32 cc = cb; int b12 = 0;
    for (int r = ts * 16; r < 4096; ++r) {
      int bin = 4095 - r;
      u32 acc = 0;
      for (int sub = 0; sub < NSUB; ++sub) acc += P[bin * NSUB + sub];
      if (cc + acc >= PRE) { b12 = bin; break; }
      cc += acc;
    }
    info[8 + b] = ((u32)b12) << 20;                    /* coarse threshold T32 */
  }
}

/* ---------- 3. compact candidates (key >= T), float4-vectorized ---------- */
__global__ __launch_bounds__(256) void k_compact(const float4* __restrict__ scores4,
                                                 const u32* __restrict__ info,
                                                 u32* __restrict__ bcnt,
                                                 u64* __restrict__ cand) {
  int t = blockIdx.x * 256 + threadIdx.x;              /* 0 .. B*ANUM/4-1 */
  int b = t >> 15;
  int e0 = (t & 32767) * 4;
  int bucket = (blockIdx.x >> 1) & (NBUCK - 1);        /* 2 blocks/bucket */
  u32 T = info[8 + b];
  float4 v = scores4[t];
  float fv[4] = {v.x, v.y, v.z, v.w};
#pragma unroll
  for (int q = 0; q < 4; ++q) {
    u32 key = score_key(fv[q]);
    if (key >= T) {
      u32 pos = atomicAdd(&bcnt[(u32)((b << 6) + bucket) * 16u], 1u);
      if (pos < BCAP)
        cand[(size_t)((b << 6) + bucket) * BCAP + pos] =
            ((u64)key << 32) | (u32)(~(u32)(e0 + q));
    }
  }
}

/* ---------- 4. gather buckets into dense zero-padded list (+zero rankbuf) ---------- */
__global__ __launch_bounds__(1024) void k_gather(const u64* __restrict__ cand,
                                                 const u32* __restrict__ bcnt,
                                                 u64* __restrict__ dense,
                                                 u32* __restrict__ rankbuf,
                                                 u32* __restrict__ info) {
  int b = blockIdx.x, tid = threadIdx.x;
  __shared__ u32 pref[NBUCK + 1];
  if (tid < NBUCK) {
    u32 c = bcnt[(u32)((b << 6) + tid) * 16u];
    if (c > BCAP) c = BCAP;
    u32 inc = c;
#pragma unroll
    for (int d = 1; d < 64; d <<= 1) {
      u32 v = __shfl_up(inc, d);
      if (tid >= d) inc += v;
    }
    pref[tid + 1] = inc;
    if (tid == 0) pref[0] = 0;
  }
  for (int i = tid; i < CAP; i += 1024) rankbuf[(size_t)b * CAP + i] = 0u;
  __syncthreads();
  u32 total = pref[NBUCK]; if (total > CAP) total = CAP;
  if (tid == 0) info[20 + b] = total;
  for (int i = tid; i < CAP; i += 1024) dense[(size_t)b * CAP + i] = 0ull;
  __syncthreads();
  for (int j = tid; j < NBUCK * BCAP; j += 1024) {
    int bk = j >> 8, sl = j & (BCAP - 1);
    u32 c = pref[bk + 1] - pref[bk];
    u32 pos = pref[bk] + (u32)sl;
    if ((u32)sl < c && pos < CAP) dense[(size_t)b * CAP + pos] = cand[(size_t)((b << 6) + bk) * BCAP + sl];
  }
}

/* ---------- 5a. partial rank-by-counting: key-blocks x comparand-splits ---------- */
__global__ __launch_bounds__(256) void k_rank_part(const u64* __restrict__ dense,
                                                   const u32* __restrict__ info,
                                                   u32* __restrict__ rankbuf) {
  int b = blockIdx.z;
  int tid = threadIdx.x;
  int i = blockIdx.x * 256 + tid;
  int n = (int)info[20 + b];
  if (blockIdx.x * 256 >= n) return;                   /* key block entirely in pad */
  int ntile = (n + 63) >> 6;
  int tper = (ntile + NSPLIT - 1) / NSPLIT;
  int t0 = blockIdx.y * tper;
  if (t0 >= ntile) return;
  int t1 = t0 + tper; if (t1 > ntile) t1 = ntile;
  const u64* Kp = dense + (size_t)b * CAP;
  u64 mykey = Kp[i];
  int lane = tid & 63;
  int rank = 0;
  for (int t = t0; t < t1; ++t) {
    u64 kv = Kp[t * 64 + lane];                        /* coalesced per-lane tile */
    u32 klo = (u32)kv, khi = (u32)(kv >> 32);
#pragma unroll
    for (int l = 0; l < 64; ++l) {
      u32 slo = (u32)__builtin_amdgcn_readlane((int)klo, l);
      u32 shi = (u32)__builtin_amdgcn_readlane((int)khi, l);
      u64 sk = ((u64)shi << 32) | (u64)slo;
      rank += (sk > mykey) ? 1 : 0;
    }
  }
  if (rank) atomicAdd(&rankbuf[(size_t)b * CAP + i], (u32)rank);
}

/* ---------- 5b. scatter + box regression fused (no FMA contraction) ---------- */
__global__ __launch_bounds__(256) void k_rankreg(const u64* __restrict__ dense,
                                                 const u32* __restrict__ rankbuf,
                                                 const u32* __restrict__ info,
                                                 const float* __restrict__ anchors,
                                                 const float* __restrict__ deltas,
                                                 float* __restrict__ scoresel,
                                                 float* __restrict__ boxes) {
  int b = blockIdx.y;
  int i = blockIdx.x * 256 + threadIdx.x;
  int n = (int)info[20 + b];
  if (i >= n) return;
  u64 mykey = dense[(size_t)b * CAP + i];
  u32 rank = rankbuf[(size_t)b * CAP + i];
  if ((u32)mykey == 0u || rank >= PRE) return;
  u32 key = (u32)(mykey >> 32);
  u32 e = ~((u32)mykey);
  u32 u = (key & 0x80000000u) ? (key ^ 0x80000000u) : ~key;
  scoresel[b * PRE + rank] = __uint_as_float(u);
  const float* an = anchors + (size_t)e * 6;
  const float* de = deltas + ((size_t)b * ANUM + e) * 6;
  float* ob = boxes + ((size_t)b * PRE + rank) * 6;
#pragma unroll
  for (int d = 0; d < 3; ++d) {
    float lo = an[d], hi = an[3 + d];
    float dims = __fsub_rn(hi, lo);
    float ctr = __fadd_rn(lo, __fmul_rn(0.5f, dims));
    ctr = __fadd_rn(ctr, __fmul_rn(de[d], dims));
    float nd = __fmul_rn(dims, expf(de[3 + d]));
    float h = __fmul_rn(0.5f, nd);
    ob[d] = __fsub_rn(ctr, h);
    ob[3 + d] = __fadd_rn(ctr, h);
  }
}

/* ---------- 6. suppression bitmask matrix — UPPER TRIANGLE ONLY ---------- */
__global__ void k_mask(const float* __restrict__ boxes, u64* __restrict__ masks,
                       u64* __restrict__ diag, u64* __restrict__ rownz) {
  int jblk = blockIdx.x, iblk = blockIdx.y, b = blockIdx.z;
  if (jblk < iblk) return;                             /* uniform whole-block exit */
  int tid = threadIdx.x;                                /* 64 */
  __shared__ float cb[64][7];
  int j0 = jblk * 64;
  {
    int jj = j0 + tid; if (jj > PRE - 1) jj = PRE - 1;
    const float* src = boxes + ((size_t)b * PRE + jj) * 6;
#pragma unroll
    for (int d = 0; d < 6; ++d) cb[tid][d] = src[d];
    float dx = fmaxf(__fsub_rn(cb[tid][3], cb[tid][0]), 0.0f);
    float dy = fmaxf(__fsub_rn(cb[tid][4], cb[tid][1]), 0.0f);
    float dz = fmaxf(__fsub_rn(cb[tid][5], cb[tid][2]), 0.0f);
    cb[tid][6] = __fmul_rn(__fmul_rn(dx, dy), dz);
  }
  __syncthreads();
  int i = iblk * 64 + tid;
  if (i >= PRE) return;
  u64 bits = 0;
  if (j0 + 63 > i) {
    const float* rb = boxes + ((size_t)b * PRE + i) * 6;
    float l0 = rb[0], l1 = rb[1], l2 = rb[2], h0 = rb[3], h1 = rb[4], h2 = rb[5];
    float dx = fmaxf(__fsub_rn(h0, l0), 0.0f);
    float dy = fmaxf(__fsub_rn(h1, l1), 0.0f);
    float dz = fmaxf(__fsub_rn(h2, l2), 0.0f);
    float vi = __fmul_rn(__fmul_rn(dx, dy), dz);
    for (int c = 0; c < 64; ++c) {
      int j = j0 + c;
      if (j > i && j < PRE) {
        float ix = fmaxf(__fsub_rn(fminf(h0, cb[c][3]), fmaxf(l0, cb[c][0])), 0.0f);
        float iy = fmaxf(__fsub_rn(fminf(h1, cb[c][4]), fmaxf(l1, cb[c][1])), 0.0f);
        float iz = fmaxf(__fsub_rn(fminf(h2, cb[c][5]), fmaxf(l2, cb[c][2])), 0.0f);
        float iv = __fmul_rn(__fmul_rn(ix, iy), iz);
        float un = fmaxf(__fsub_rn(__fadd_rn(vi, cb[c][6]), iv), 1e-8f);
        float iou = __fdiv_rn(iv, un);
        if (iou > 0.7f) bits |= (1ull << c);
      }
    }
  }
  masks[((size_t)b * PRE + i) * MROW + jblk] = bits;
  if (iblk == jblk) diag[((size_t)b * NW + jblk) * 64 + tid] = bits;
  u64 bal = __ballot(bits != 0ull);
  if (tid == 0 && bal) atomicOr(&rownz[b * NW + iblk], bal);
}

/* ---------- 7. sparse single-wave NMS scan + output-assembly tail ---------- */
__global__ __launch_bounds__(64) void k_scan(const u64* __restrict__ masks,
                                             const u64* __restrict__ diag,
                                             const u64* __restrict__ rownz,
                                             u32* __restrict__ kept,
                                             u32* __restrict__ info,
                                             const float* __restrict__ boxes,
                                             const float* __restrict__ scoresel,
                                             float* __restrict__ out) {
  int b = blockIdx.x;
  int lane = threadIdx.x;                               /* 64 */
  const u64* Mb = masks + (size_t)b * PRE * MROW;
  const u64* Db = diag + (size_t)b * NW * 64;
  const u64* Nb = rownz + b * NW;
  int wl = lane < NW ? lane : NW - 1;
  u64 rem = 0;
  int cnt = 0;

  u64 dcur = Db[lane];
  u64 nzcur = Nb[0];

  for (int c = 0; c < NW; ++c) {
    int base = c * 64;
    int nrow = (base + 64 <= PRE) ? 64 : (PRE - base);

    u64 dn = (c + 1 < NW) ? Db[(size_t)(c + 1) * 64 + lane] : 0ull;
    u64 nzn = (c + 1 < NW) ? Nb[c + 1] : 0ull;

    u32 rlo = __shfl((u32)rem, c);
    u32 rhi = __shfl((u32)(rem >> 32), c);
    u64 pending = ~(((u64)rhi << 32) | (u64)rlo);
    if (nrow < 64) pending &= ((1ull << nrow) - 1ull);

    u64 Z = __ballot(dcur != 0ull);
    u64 chain = pending & Z;
    while (chain) {
      int k = __builtin_ctzll(chain);
      u32 rl = (u32)__builtin_amdgcn_readlane((int)(u32)dcur, k);
      u32 rh = (u32)__builtin_amdgcn_readlane((int)(u32)(dcur >> 32), k);
      u64 rw = ((u64)rh << 32) | (u64)rl;
      pending &= ~rw;
      chain &= pending;
      chain &= ~(1ull << k);
    }
    u64 keep = pending;

    u64 ltmask = (lane == 0) ? 0ull : (~0ull >> (64 - lane));
    int pos = __popcll(keep & ltmask);
    if ((keep >> lane) & 1ull) kept[b * PRE + cnt + pos] = (u32)(base + lane);
    cnt += (int)__popcll(keep);

    if (cnt >= MAXOUT) break;

    u64 nz = keep & nzcur;
    while (nz) {
      int rks[8]; int m = 0; int rr = base;
#pragma unroll
      for (int s = 0; s < 8; ++s) {
        if (nz) { rr = base + __builtin_ctzll(nz); nz &= nz - 1; ++m; }
        rks[s] = rr;
      }
      u64 v[8];
#pragma unroll
      for (int s = 0; s < 8; ++s) v[s] = Mb[(size_t)rks[s] * MROW + wl];
      u64 acc = 0;
#pragma unroll
      for (int s = 0; s < 8; ++s) acc |= (s < m) ? v[s] : 0ull;
      rem |= acc;
    }

    dcur = dn;
    nzcur = nzn;
  }
  if (lane == 0) info[16 + b] = (u32)cnt;
  __syncthreads();                                     /* drain kept[] stores */

  /* ---- output assembly tail (same wave; same-block data only) ---- */
  int cc = cnt > MAXOUT ? MAXOUT : cnt;
  for (int k = lane; k < MAXOUT; k += 64) {
    float pr[6] = {0.f, 0.f, 0.f, 0.f, 0.f, 0.f};
    float s = 0.f, vfl = 0.f;
    if (k < cc) {
      u32 i = kept[b * PRE + k];
      const float* bx = boxes + ((size_t)b * PRE + i) * 6;
#pragma unroll
      for (int d = 0; d < 6; ++d) pr[d] = bx[d];
      s = scoresel[b * PRE + i];
      vfl = 1.f;
    }
    float* pp = out + ((size_t)(b * MAXOUT + k)) * 6;
#pragma unroll
    for (int d = 0; d < 6; ++d) pp[d] = pr[d];
    out[BATCH * MAXOUT * 6 + b * MAXOUT + k] = s;
    out[BATCH * MAXOUT * 7 + b * MAXOUT + k] = (float)b;
    out[BATCH * MAXOUT * 8 + b * MAXOUT + k] = vfl;
  }
}

extern "C" void kernel_launch(void* const* d_in, const int* in_sizes, int n_in,
                              void* d_out, int out_size, void* d_ws, size_t ws_size,
                              hipStream_t stream) {
  const float* anchors = (const float*)d_in[0];
  const float* scores  = (const float*)d_in[1];
  const float* deltas  = (const float*)d_in[2];
  float* out = (float*)d_out;

  char* w = (char*)d_ws;
  u32* part    = (u32*)(w + OFF_PART);
  u64* cand    = (u64*)(w + OFF_CAND);
  u64* diag    = (u64*)(w + OFF_DIAG);
  u64* dense   = (u64*)(w + OFF_DENSE);
  u32* rankbuf = (u32*)(w + OFF_RANKB);
  u32* info    = (u32*)(w + OFF_INFO);
  u64* rownz   = (u64*)(w + OFF_ROWNZ);
  u32* bcnt    = (u32*)(w + OFF_BCNT);
  float* scoresel = (float*)(w + OFF_SCORE);
  float* boxes = (float*)(w + OFF_BOXES);
  u64* masks   = (u64*)(w + OFF_MASKS);
  u32* kept    = (u32*)(w + OFF_KEPT);

  k_h12<<<BATCH * NSUB, 256, 0, stream>>>(scores, part, (u32*)(w + OFF_ROWNZ));
  k_sel12<<<BATCH, 256, 0, stream>>>(part, info);
  k_compact<<<BATCH * ANUM / 4 / 256, 256, 0, stream>>>((const float4*)scores, info, bcnt, cand);
  k_gather<<<BATCH, 1024, 0, stream>>>(cand, bcnt, dense, rankbuf, info);
  k_rank_part<<<dim3(CAP / 256, NSPLIT, BATCH), 256, 0, stream>>>(dense, info, rankbuf);
  k_rankreg<<<dim3(CAP / 256, BATCH), 256, 0, stream>>>(dense, rankbuf, info, anchors, deltas,
                                                        scoresel, boxes);
  k_mask<<<dim3(NW, NW, BATCH), 64, 0, stream>>>(boxes, masks, diag, rownz);
  k_scan<<<BATCH, 64, 0, stream>>>(masks, diag, rownz, kept, info, boxes, scoresel, out);
}

// Round 19
// 93.245 us; speedup vs baseline: 2.4397x; 1.1228x over previous
//
#include <hip/hip_runtime.h>
#include <hip/hip_bf16.h>
#include <cstdint>

typedef unsigned int u32;
typedef unsigned long long u64;

#define ANUM 131072
#define BATCH 4
#define PRE 3000
#define CAP 8192       /* candidate slack: threshold is bin-floor (coarse), rank fixes order */
#define NW 47          /* ceil(3000/64) */
#define NPAIR 1128     /* NW*(NW+1)/2 upper-triangle block pairs */
#define MROW 48        /* padded u64 words per mask row */
#define MAXOUT 1000
#define NBUCK 64       /* candidate buckets per batch */
#define BCAP 256       /* slots per bucket (lambda~69, overflow impossible) */
#define NSUB 16        /* histogram sub-blocks per batch */
#define NSPLIT 8       /* comparand splits in k_rank_part */

/* ---- workspace layout (bytes) ---- */
#define OFF_PART   0ul                 /* u32[B][4096][NSUB] = 1MB */
#define OFF_CAND   0ul                 /* u64[B][NBUCK][BCAP] = 512KB (aliases part) */
#define OFF_DIAG   1048576ul           /* u64[B][NW][64] = 96256 */
#define OFF_DENSE  1179648ul           /* u64[B][CAP] = 262144 -> ends 1441792 */
#define OFF_RANKB  1441792ul           /* u32[B][CAP] = 131072 -> ends 1572864 */
#define OFF_INFO   2097152ul           /* u32[256]: [8..11]=T32 [16..19]=keptcnt [20..23]=total */
#define OFF_ROWNZ  2098176ul           /* u64[B][NW]=1504 -> pad 2KB (zeroed by k_h12 blk0) */
#define OFF_BCNT   2100224ul           /* u32[B*NBUCK*16] = 16KB (zeroed by k_h12 blk0) */
#define OFF_SCORE  2164608ul           /* f32[B][PRE] */
#define OFF_BOXES  2212608ul           /* f32[B][PRE][6] */
#define OFF_MASKS  2500608ul           /* u64[B][PRE][MROW] = 4608000 */
#define OFF_KEPT   7108608ul           /* u32[B][PRE] -> end 7156608 */
#define ZERO_WORDS 4608                /* (rownz pad 2KB + bcnt 16KB) / 4 */

__device__ __forceinline__ u32 score_key(float f) {
  u32 u = __float_as_uint(f);
  return (u & 0x80000000u) ? ~u : (u | 0x80000000u);
}

/* ---------- 1. 12-bit LDS-privatized histogram + zero-init of atomics ---------- */
__global__ __launch_bounds__(256) void k_h12(const float* __restrict__ scores,
                                             u32* __restrict__ part,
                                             u32* __restrict__ zr /* rownz+bcnt */) {
  __shared__ u32 lh[4096];
  int b = blockIdx.x >> 4, sub = blockIdx.x & (NSUB - 1);
  int tid = threadIdx.x;
  if (blockIdx.x == 0) {                               /* zero rownz+bcnt (18KB) */
#pragma unroll
    for (int i = 0; i < ZERO_WORDS / 256; ++i) zr[i * 256 + tid] = 0u;
  }
  for (int i = tid; i < 4096; i += 256) lh[i] = 0;
  __syncthreads();
  const float4* src = (const float4*)(scores + (size_t)b * ANUM) + (size_t)sub * 2048;
#pragma unroll
  for (int it = 0; it < 8; ++it) {
    float4 v = src[it * 256 + tid];
    atomicAdd(&lh[score_key(v.x) >> 20], 1u);
    atomicAdd(&lh[score_key(v.y) >> 20], 1u);
    atomicAdd(&lh[score_key(v.z) >> 20], 1u);
    atomicAdd(&lh[score_key(v.w) >> 20], 1u);
  }
  __syncthreads();
  u32* P = part + (size_t)b * 4096 * NSUB;
  for (int i = tid; i < 4096; i += 256) P[i * NSUB + sub] = lh[i];
}

/* ---------- 2. find 12-bit bin crossing rank 3000 -> coarse threshold T ---------- */
__global__ void k_sel12(const u32* __restrict__ part, u32* __restrict__ info) {
  int b = blockIdx.x, tid = threadIdx.x;              /* 256 threads */
  __shared__ u32 strip[256];
  const u32* P = part + (size_t)b * 4096 * NSUB;
  u32 s = 0;
  for (int j = 0; j < 16; ++j) {
    int bin = 4095 - (tid * 16 + j);
    u32 acc = 0;
#pragma unroll
    for (int sub = 0; sub < NSUB; ++sub) acc += P[bin * NSUB + sub];
    s += acc;
  }
  strip[tid] = s;
  __syncthreads();
  if (tid == 0) {
    u32 c = 0; int ts = 0; u32 cb = 0;
    for (int t = 0; t < 256; ++t) {
      if (c + strip[t] >= PRE) { ts = t; cb = c; break; }
      c += strip[t];
    }
    u32 cc = cb; int b12 = 0;
    for (int r = ts * 16; r < 4096; ++r) {
      int bin = 4095 - r;
      u32 acc = 0;
      for (int sub = 0; sub < NSUB; ++sub) acc += P[bin * NSUB + sub];
      if (cc + acc >= PRE) { b12 = bin; break; }
      cc += acc;
    }
    info[8 + b] = ((u32)b12) << 20;                    /* coarse threshold T32 */
  }
}

/* ---------- 3. compact candidates (key >= T), float4-vectorized ---------- */
__global__ __launch_bounds__(256) void k_compact(const float4* __restrict__ scores4,
                                                 const u32* __restrict__ info,
                                                 u32* __restrict__ bcnt,
                                                 u64* __restrict__ cand) {
  int t = blockIdx.x * 256 + threadIdx.x;              /* 0 .. B*ANUM/4-1 */
  int b = t >> 15;
  int e0 = (t & 32767) * 4;
  int bucket = (blockIdx.x >> 1) & (NBUCK - 1);        /* 2 blocks/bucket */
  u32 T = info[8 + b];
  float4 v = scores4[t];
  float fv[4] = {v.x, v.y, v.z, v.w};
#pragma unroll
  for (int q = 0; q < 4; ++q) {
    u32 key = score_key(fv[q]);
    if (key >= T) {
      u32 pos = atomicAdd(&bcnt[(u32)((b << 6) + bucket) * 16u], 1u);
      if (pos < BCAP)
        cand[(size_t)((b << 6) + bucket) * BCAP + pos] =
            ((u64)key << 32) | (u32)(~(u32)(e0 + q));
    }
  }
}

/* ---------- 4. gather buckets into dense zero-padded list (+zero rankbuf) ---------- */
__global__ __launch_bounds__(1024) void k_gather(const u64* __restrict__ cand,
                                                 const u32* __restrict__ bcnt,
                                                 u64* __restrict__ dense,
                                                 u32* __restrict__ rankbuf,
                                                 u32* __restrict__ info) {
  int b = blockIdx.x, tid = threadIdx.x;
  __shared__ u32 pref[NBUCK + 1];
  if (tid < NBUCK) {
    u32 c = bcnt[(u32)((b << 6) + tid) * 16u];
    if (c > BCAP) c = BCAP;
    u32 inc = c;
#pragma unroll
    for (int d = 1; d < 64; d <<= 1) {
      u32 v = __shfl_up(inc, d);
      if (tid >= d) inc += v;
    }
    pref[tid + 1] = inc;
    if (tid == 0) pref[0] = 0;
  }
  for (int i = tid; i < CAP; i += 1024) rankbuf[(size_t)b * CAP + i] = 0u;
  __syncthreads();
  u32 total = pref[NBUCK]; if (total > CAP) total = CAP;
  if (tid == 0) info[20 + b] = total;
  for (int i = tid; i < CAP; i += 1024) dense[(size_t)b * CAP + i] = 0ull;
  __syncthreads();
  for (int j = tid; j < NBUCK * BCAP; j += 1024) {
    int bk = j >> 8, sl = j & (BCAP - 1);
    u32 c = pref[bk + 1] - pref[bk];
    u32 pos = pref[bk] + (u32)sl;
    if ((u32)sl < c && pos < CAP) dense[(size_t)b * CAP + pos] = cand[(size_t)((b << 6) + bk) * BCAP + sl];
  }
}

/* ---------- 5a. partial rank-by-counting: key-blocks x comparand-splits ---------- */
__global__ __launch_bounds__(256) void k_rank_part(const u64* __restrict__ dense,
                                                   const u32* __restrict__ info,
                                                   u32* __restrict__ rankbuf) {
  int b = blockIdx.z;
  int tid = threadIdx.x;
  int i = blockIdx.x * 256 + tid;
  int n = (int)info[20 + b];
  if (blockIdx.x * 256 >= n) return;                   /* key block entirely in pad */
  int ntile = (n + 63) >> 6;
  int tper = (ntile + NSPLIT - 1) / NSPLIT;
  int t0 = blockIdx.y * tper;
  if (t0 >= ntile) return;
  int t1 = t0 + tper; if (t1 > ntile) t1 = ntile;
  const u64* Kp = dense + (size_t)b * CAP;
  u64 mykey = Kp[i];
  int lane = tid & 63;
  int rank = 0;
  for (int t = t0; t < t1; ++t) {
    u64 kv = Kp[t * 64 + lane];                        /* coalesced per-lane tile */
    u32 klo = (u32)kv, khi = (u32)(kv >> 32);
#pragma unroll
    for (int l = 0; l < 64; ++l) {
      u32 slo = (u32)__builtin_amdgcn_readlane((int)klo, l);
      u32 shi = (u32)__builtin_amdgcn_readlane((int)khi, l);
      u64 sk = ((u64)shi << 32) | (u64)slo;
      rank += (sk > mykey) ? 1 : 0;
    }
  }
  if (rank) atomicAdd(&rankbuf[(size_t)b * CAP + i], (u32)rank);
}

/* ---------- 5b. scatter + box regression fused (no FMA contraction) ---------- */
__global__ __launch_bounds__(256) void k_rankreg(const u64* __restrict__ dense,
                                                 const u32* __restrict__ rankbuf,
                                                 const u32* __restrict__ info,
                                                 const float* __restrict__ anchors,
                                                 const float* __restrict__ deltas,
                                                 float* __restrict__ scoresel,
                                                 float* __restrict__ boxes) {
  int b = blockIdx.y;
  int i = blockIdx.x * 256 + threadIdx.x;
  int n = (int)info[20 + b];
  if (i >= n) return;
  u64 mykey = dense[(size_t)b * CAP + i];
  u32 rank = rankbuf[(size_t)b * CAP + i];
  if ((u32)mykey == 0u || rank >= PRE) return;
  u32 key = (u32)(mykey >> 32);
  u32 e = ~((u32)mykey);
  u32 u = (key & 0x80000000u) ? (key ^ 0x80000000u) : ~key;
  scoresel[b * PRE + rank] = __uint_as_float(u);
  const float* an = anchors + (size_t)e * 6;
  const float* de = deltas + ((size_t)b * ANUM + e) * 6;
  float* ob = boxes + ((size_t)b * PRE + rank) * 6;
#pragma unroll
  for (int d = 0; d < 3; ++d) {
    float lo = an[d], hi = an[3 + d];
    float dims = __fsub_rn(hi, lo);
    float ctr = __fadd_rn(lo, __fmul_rn(0.5f, dims));
    ctr = __fadd_rn(ctr, __fmul_rn(de[d], dims));
    float nd = __fmul_rn(dims, expf(de[3 + d]));
    float h = __fmul_rn(0.5f, nd);
    ob[d] = __fsub_rn(ctr, h);
    ob[3 + d] = __fadd_rn(ctr, h);
  }
}

/* ---------- 6. suppression bitmask — triangular linear grid ----------
 * blockIdx.x = L in [0, NPAIR); decode jblk = max r with r(r+1)/2 <= L,
 * iblk = L - r(r+1)/2 (iblk <= jblk). Lower-triangle words stay unwritten
 * (garbage) — safe: word w of a chunk-c' row only enters rem[w] during
 * chunk c' > w, after chunk w was consumed.
 */
__global__ void k_mask(const float* __restrict__ boxes, u64* __restrict__ masks,
                       u64* __restrict__ diag, u64* __restrict__ rownz) {
  int L = blockIdx.x, b = blockIdx.y;
  int r = (int)((sqrtf(8.0f * (float)L + 1.0f) - 1.0f) * 0.5f);
  while ((r + 1) * (r + 2) / 2 <= L) ++r;
  while (r * (r + 1) / 2 > L) --r;
  int jblk = r, iblk = L - r * (r + 1) / 2;            /* iblk <= jblk */
  int tid = threadIdx.x;                                /* 64 */
  __shared__ float cb[64][7];
  int j0 = jblk * 64;
  {
    int jj = j0 + tid; if (jj > PRE - 1) jj = PRE - 1;
    const float* src = boxes + ((size_t)b * PRE + jj) * 6;
#pragma unroll
    for (int d = 0; d < 6; ++d) cb[tid][d] = src[d];
    float dx = fmaxf(__fsub_rn(cb[tid][3], cb[tid][0]), 0.0f);
    float dy = fmaxf(__fsub_rn(cb[tid][4], cb[tid][1]), 0.0f);
    float dz = fmaxf(__fsub_rn(cb[tid][5], cb[tid][2]), 0.0f);
    cb[tid][6] = __fmul_rn(__fmul_rn(dx, dy), dz);
  }
  __syncthreads();
  int i = iblk * 64 + tid;
  if (i >= PRE) return;
  u64 bits = 0;
  if (j0 + 63 > i) {
    const float* rb = boxes + ((size_t)b * PRE + i) * 6;
    float l0 = rb[0], l1 = rb[1], l2 = rb[2], h0 = rb[3], h1 = rb[4], h2 = rb[5];
    float dx = fmaxf(__fsub_rn(h0, l0), 0.0f);
    float dy = fmaxf(__fsub_rn(h1, l1), 0.0f);
    float dz = fmaxf(__fsub_rn(h2, l2), 0.0f);
    float vi = __fmul_rn(__fmul_rn(dx, dy), dz);
    for (int c = 0; c < 64; ++c) {
      int j = j0 + c;
      if (j > i && j < PRE) {
        float ix = fmaxf(__fsub_rn(fminf(h0, cb[c][3]), fmaxf(l0, cb[c][0])), 0.0f);
        float iy = fmaxf(__fsub_rn(fminf(h1, cb[c][4]), fmaxf(l1, cb[c][1])), 0.0f);
        float iz = fmaxf(__fsub_rn(fminf(h2, cb[c][5]), fmaxf(l2, cb[c][2])), 0.0f);
        float iv = __fmul_rn(__fmul_rn(ix, iy), iz);
        float un = fmaxf(__fsub_rn(__fadd_rn(vi, cb[c][6]), iv), 1e-8f);
        float iou = __fdiv_rn(iv, un);
        if (iou > 0.7f) bits |= (1ull << c);
      }
    }
  }
  masks[((size_t)b * PRE + i) * MROW + jblk] = bits;
  if (iblk == jblk) diag[((size_t)b * NW + jblk) * 64 + tid] = bits;
  u64 bal = __ballot(bits != 0ull);
  if (tid == 0 && bal) atomicOr(&rownz[b * NW + iblk], bal);
}

/* ---------- 7. sparse single-wave NMS scan ---------- */
__global__ __launch_bounds__(64) void k_scan(const u64* __restrict__ masks,
                                             const u64* __restrict__ diag,
                                             const u64* __restrict__ rownz,
                                             u32* __restrict__ kept,
                                             u32* __restrict__ info) {
  int b = blockIdx.x;
  int lane = threadIdx.x;                               /* 64 */
  const u64* Mb = masks + (size_t)b * PRE * MROW;
  const u64* Db = diag + (size_t)b * NW * 64;
  const u64* Nb = rownz + b * NW;
  int wl = lane < NW ? lane : NW - 1;
  u64 rem = 0;
  int cnt = 0;

  u64 dcur = Db[lane];
  u64 nzcur = Nb[0];

  for (int c = 0; c < NW; ++c) {
    int base = c * 64;
    int nrow = (base + 64 <= PRE) ? 64 : (PRE - base);

    u64 dn = (c + 1 < NW) ? Db[(size_t)(c + 1) * 64 + lane] : 0ull;
    u64 nzn = (c + 1 < NW) ? Nb[c + 1] : 0ull;

    u32 rlo = __shfl((u32)rem, c);
    u32 rhi = __shfl((u32)(rem >> 32), c);
    u64 pending = ~(((u64)rhi << 32) | (u64)rlo);
    if (nrow < 64) pending &= ((1ull << nrow) - 1ull);

    u64 Z = __ballot(dcur != 0ull);
    u64 chain = pending & Z;
    while (chain) {
      int k = __builtin_ctzll(chain);
      u32 rl = (u32)__builtin_amdgcn_readlane((int)(u32)dcur, k);
      u32 rh = (u32)__builtin_amdgcn_readlane((int)(u32)(dcur >> 32), k);
      u64 rw = ((u64)rh << 32) | (u64)rl;
      pending &= ~rw;
      chain &= pending;
      chain &= ~(1ull << k);
    }
    u64 keep = pending;

    u64 ltmask = (lane == 0) ? 0ull : (~0ull >> (64 - lane));
    int pos = __popcll(keep & ltmask);
    if ((keep >> lane) & 1ull) kept[b * PRE + cnt + pos] = (u32)(base + lane);
    cnt += (int)__popcll(keep);

    if (cnt >= MAXOUT) break;

    u64 nz = keep & nzcur;
    while (nz) {
      int rks[8]; int m = 0; int rr = base;
#pragma unroll
      for (int s = 0; s < 8; ++s) {
        if (nz) { rr = base + __builtin_ctzll(nz); nz &= nz - 1; ++m; }
        rks[s] = rr;
      }
      u64 v[8];
#pragma unroll
      for (int s = 0; s < 8; ++s) v[s] = Mb[(size_t)rks[s] * MROW + wl];
      u64 acc = 0;
#pragma unroll
      for (int s = 0; s < 8; ++s) acc |= (s < m) ? v[s] : 0ull;
      rem |= acc;
    }

    dcur = dn;
    nzcur = nzn;
  }
  if (lane == 0) info[16 + b] = (u32)cnt;
}

/* ---------- 8. output assembly ---------- */
__global__ void k_out(const float* __restrict__ boxes, const float* __restrict__ scoresel,
                      const u32* __restrict__ kept, const u32* __restrict__ info,
                      float* __restrict__ out) {
  int b = blockIdx.x, tid = threadIdx.x;                /* 256 */
  int cnt = (int)info[16 + b]; if (cnt > MAXOUT) cnt = MAXOUT;
  for (int k = tid; k < MAXOUT; k += 256) {
    float pr[6] = {0.f, 0.f, 0.f, 0.f, 0.f, 0.f};
    float s = 0.f, v = 0.f;
    if (k < cnt) {
      u32 i = kept[b * PRE + k];
      const float* bx = boxes + ((size_t)b * PRE + i) * 6;
#pragma unroll
      for (int d = 0; d < 6; ++d) pr[d] = bx[d];
      s = scoresel[b * PRE + i];
      v = 1.f;
    }
    float* pp = out + ((size_t)(b * MAXOUT + k)) * 6;
#pragma unroll
    for (int d = 0; d < 6; ++d) pp[d] = pr[d];
    out[BATCH * MAXOUT * 6 + b * MAXOUT + k] = s;
    out[BATCH * MAXOUT * 7 + b * MAXOUT + k] = (float)b;
    out[BATCH * MAXOUT * 8 + b * MAXOUT + k] = v;
  }
}

extern "C" void kernel_launch(void* const* d_in, const int* in_sizes, int n_in,
                              void* d_out, int out_size, void* d_ws, size_t ws_size,
                              hipStream_t stream) {
  const float* anchors = (const float*)d_in[0];
  const float* scores  = (const float*)d_in[1];
  const float* deltas  = (const float*)d_in[2];
  float* out = (float*)d_out;

  char* w = (char*)d_ws;
  u32* part    = (u32*)(w + OFF_PART);
  u64* cand    = (u64*)(w + OFF_CAND);
  u64* diag    = (u64*)(w + OFF_DIAG);
  u64* dense   = (u64*)(w + OFF_DENSE);
  u32* rankbuf = (u32*)(w + OFF_RANKB);
  u32* info    = (u32*)(w + OFF_INFO);
  u64* rownz   = (u64*)(w + OFF_ROWNZ);
  u32* bcnt    = (u32*)(w + OFF_BCNT);
  float* scoresel = (float*)(w + OFF_SCORE);
  float* boxes = (float*)(w + OFF_BOXES);
  u64* masks   = (u64*)(w + OFF_MASKS);
  u32* kept    = (u32*)(w + OFF_KEPT);

  k_h12<<<BATCH * NSUB, 256, 0, stream>>>(scores, part, (u32*)(w + OFF_ROWNZ));
  k_sel12<<<BATCH, 256, 0, stream>>>(part, info);
  k_compact<<<BATCH * ANUM / 4 / 256, 256, 0, stream>>>((const float4*)scores, info, bcnt, cand);
  k_gather<<<BATCH, 1024, 0, stream>>>(cand, bcnt, dense, rankbuf, info);
  k_rank_part<<<dim3(CAP / 256, NSPLIT, BATCH), 256, 0, stream>>>(dense, info, rankbuf);
  k_rankreg<<<dim3(CAP / 256, BATCH), 256, 0, stream>>>(dense, rankbuf, info, anchors, deltas,
                                                        scoresel, boxes);
  k_mask<<<dim3(NPAIR, BATCH), 64, 0, stream>>>(boxes, masks, diag, rownz);
  k_scan<<<BATCH, 64, 0, stream>>>(masks, diag, rownz, kept, info);
  k_out<<<BATCH, 256, 0, stream>>>(boxes, scoresel, kept, info, out);
}

// Round 20
// 91.478 us; speedup vs baseline: 2.4868x; 1.0193x over previous
//
#include <hip/hip_runtime.h>
#include <hip/hip_bf16.h>
#include <cstdint>

typedef unsigned int u32;
typedef unsigned long long u64;

#define ANUM 131072
#define BATCH 4
#define PRE 3000
#define CAP 8192       /* candidate slack: threshold is bin-floor (coarse), rank fixes order */
#define NW 47          /* ceil(3000/64) */
#define NPAIR 1128     /* NW*(NW+1)/2 upper-triangle block pairs */
#define MROW 48        /* padded u64 words per mask row */
#define MAXOUT 1000
#define NBUCK 64       /* candidate buckets per batch */
#define BCAP 256       /* slots per bucket (lambda~69, overflow impossible) */
#define NSUB 16        /* histogram sub-blocks per batch */
#define NSPLIT 8       /* comparand splits in k_rank_part */

/* ---- workspace layout (bytes) ---- */
#define OFF_PART   0ul                 /* u32[B][4096][NSUB] = 1MB */
#define OFF_CAND   0ul                 /* u64[B][NBUCK][BCAP] = 512KB (aliases part) */
#define OFF_DIAG   1048576ul           /* u64[B][NW][64] = 96256 */
#define OFF_DENSE  1179648ul           /* u64[B][CAP] = 262144 -> ends 1441792 */
#define OFF_RANKB  1441792ul           /* u32[B][CAP] = 131072 -> ends 1572864 */
#define OFF_INFO   2097152ul           /* u32[256]: [8..11]=T32 [20..23]=total */
#define OFF_ROWNZ  2098176ul           /* u64[B][NW]=1504 -> pad 2KB (zeroed by k_h12 blk0) */
#define OFF_BCNT   2100224ul           /* u32[B*NBUCK*16] = 16KB (zeroed by k_h12 blk0) */
#define OFF_SCORE  2164608ul           /* f32[B][PRE] */
#define OFF_BOXES  2212608ul           /* f32[B][PRE][6] */
#define OFF_MASKS  2500608ul           /* u64[B][PRE][MROW] = 4608000 */
#define ZERO_WORDS 4608                /* (rownz pad 2KB + bcnt 16KB) / 4 */

__device__ __forceinline__ u32 score_key(float f) {
  u32 u = __float_as_uint(f);
  return (u & 0x80000000u) ? ~u : (u | 0x80000000u);
}

/* ---------- 1. 12-bit LDS-privatized histogram + zero-init of atomics ---------- */
__global__ __launch_bounds__(256) void k_h12(const float* __restrict__ scores,
                                             u32* __restrict__ part,
                                             u32* __restrict__ zr /* rownz+bcnt */) {
  __shared__ u32 lh[4096];
  int b = blockIdx.x >> 4, sub = blockIdx.x & (NSUB - 1);
  int tid = threadIdx.x;
  if (blockIdx.x == 0) {                               /* zero rownz+bcnt (18KB) */
#pragma unroll
    for (int i = 0; i < ZERO_WORDS / 256; ++i) zr[i * 256 + tid] = 0u;
  }
  for (int i = tid; i < 4096; i += 256) lh[i] = 0;
  __syncthreads();
  const float4* src = (const float4*)(scores + (size_t)b * ANUM) + (size_t)sub * 2048;
#pragma unroll
  for (int it = 0; it < 8; ++it) {
    float4 v = src[it * 256 + tid];
    atomicAdd(&lh[score_key(v.x) >> 20], 1u);
    atomicAdd(&lh[score_key(v.y) >> 20], 1u);
    atomicAdd(&lh[score_key(v.z) >> 20], 1u);
    atomicAdd(&lh[score_key(v.w) >> 20], 1u);
  }
  __syncthreads();
  u32* P = part + (size_t)b * 4096 * NSUB;
  for (int i = tid; i < 4096; i += 256) P[i * NSUB + sub] = lh[i];
}

/* ---------- 2. find 12-bit bin crossing rank 3000 -> coarse threshold T ---------- */
__global__ void k_sel12(const u32* __restrict__ part, u32* __restrict__ info) {
  int b = blockIdx.x, tid = threadIdx.x;              /* 256 threads */
  __shared__ u32 strip[256];
  const u32* P = part + (size_t)b * 4096 * NSUB;
  u32 s = 0;
  for (int j = 0; j < 16; ++j) {
    int bin = 4095 - (tid * 16 + j);
    u32 acc = 0;
#pragma unroll
    for (int sub = 0; sub < NSUB; ++sub) acc += P[bin * NSUB + sub];
    s += acc;
  }
  strip[tid] = s;
  __syncthreads();
  if (tid == 0) {
    u32 c = 0; int ts = 0; u32 cb = 0;
    for (int t = 0; t < 256; ++t) {
      if (c + strip[t] >= PRE) { ts = t; cb = c; break; }
      c += strip[t];
    }
    u32 cc = cb; int b12 = 0;
    for (int r = ts * 16; r < 4096; ++r) {
      int bin = 4095 - r;
      u32 acc = 0;
      for (int sub = 0; sub < NSUB; ++sub) acc += P[bin * NSUB + sub];
      if (cc + acc >= PRE) { b12 = bin; break; }
      cc += acc;
    }
    info[8 + b] = ((u32)b12) << 20;                    /* coarse threshold T32 */
  }
}

/* ---------- 3. compact candidates (key >= T), float4-vectorized ---------- */
__global__ __launch_bounds__(256) void k_compact(const float4* __restrict__ scores4,
                                                 const u32* __restrict__ info,
                                                 u32* __restrict__ bcnt,
                                                 u64* __restrict__ cand) {
  int t = blockIdx.x * 256 + threadIdx.x;              /* 0 .. B*ANUM/4-1 */
  int b = t >> 15;
  int e0 = (t & 32767) * 4;
  int bucket = (blockIdx.x >> 1) & (NBUCK - 1);        /* 2 blocks/bucket */
  u32 T = info[8 + b];
  float4 v = scores4[t];
  float fv[4] = {v.x, v.y, v.z, v.w};
#pragma unroll
  for (int q = 0; q < 4; ++q) {
    u32 key = score_key(fv[q]);
    if (key >= T) {
      u32 pos = atomicAdd(&bcnt[(u32)((b << 6) + bucket) * 16u], 1u);
      if (pos < BCAP)
        cand[(size_t)((b << 6) + bucket) * BCAP + pos] =
            ((u64)key << 32) | (u32)(~(u32)(e0 + q));
    }
  }
}

/* ---------- 4. gather buckets into dense zero-padded list (+zero rankbuf) ---------- */
__global__ __launch_bounds__(1024) void k_gather(const u64* __restrict__ cand,
                                                 const u32* __restrict__ bcnt,
                                                 u64* __restrict__ dense,
                                                 u32* __restrict__ rankbuf,
                                                 u32* __restrict__ info) {
  int b = blockIdx.x, tid = threadIdx.x;
  __shared__ u32 pref[NBUCK + 1];
  if (tid < NBUCK) {
    u32 c = bcnt[(u32)((b << 6) + tid) * 16u];
    if (c > BCAP) c = BCAP;
    u32 inc = c;
#pragma unroll
    for (int d = 1; d < 64; d <<= 1) {
      u32 v = __shfl_up(inc, d);
      if (tid >= d) inc += v;
    }
    pref[tid + 1] = inc;
    if (tid == 0) pref[0] = 0;
  }
  for (int i = tid; i < CAP; i += 1024) rankbuf[(size_t)b * CAP + i] = 0u;
  __syncthreads();
  u32 total = pref[NBUCK]; if (total > CAP) total = CAP;
  if (tid == 0) info[20 + b] = total;
  for (int i = tid; i < CAP; i += 1024) dense[(size_t)b * CAP + i] = 0ull;
  __syncthreads();
  for (int j = tid; j < NBUCK * BCAP; j += 1024) {
    int bk = j >> 8, sl = j & (BCAP - 1);
    u32 c = pref[bk + 1] - pref[bk];
    u32 pos = pref[bk] + (u32)sl;
    if ((u32)sl < c && pos < CAP) dense[(size_t)b * CAP + pos] = cand[(size_t)((b << 6) + bk) * BCAP + sl];
  }
}

/* ---------- 5a. partial rank-by-counting: key-blocks x comparand-splits ---------- */
__global__ __launch_bounds__(256) void k_rank_part(const u64* __restrict__ dense,
                                                   const u32* __restrict__ info,
                                                   u32* __restrict__ rankbuf) {
  int b = blockIdx.z;
  int tid = threadIdx.x;
  int i = blockIdx.x * 256 + tid;
  int n = (int)info[20 + b];
  if (blockIdx.x * 256 >= n) return;                   /* key block entirely in pad */
  int ntile = (n + 63) >> 6;
  int tper = (ntile + NSPLIT - 1) / NSPLIT;
  int t0 = blockIdx.y * tper;
  if (t0 >= ntile) return;
  int t1 = t0 + tper; if (t1 > ntile) t1 = ntile;
  const u64* Kp = dense + (size_t)b * CAP;
  u64 mykey = Kp[i];
  int lane = tid & 63;
  int rank = 0;
  for (int t = t0; t < t1; ++t) {
    u64 kv = Kp[t * 64 + lane];                        /* coalesced per-lane tile */
    u32 klo = (u32)kv, khi = (u32)(kv >> 32);
#pragma unroll
    for (int l = 0; l < 64; ++l) {
      u32 slo = (u32)__builtin_amdgcn_readlane((int)klo, l);
      u32 shi = (u32)__builtin_amdgcn_readlane((int)khi, l);
      u64 sk = ((u64)shi << 32) | (u64)slo;
      rank += (sk > mykey) ? 1 : 0;
    }
  }
  if (rank) atomicAdd(&rankbuf[(size_t)b * CAP + i], (u32)rank);
}

/* ---------- 5b. scatter + box regression fused (no FMA contraction) ---------- */
__global__ __launch_bounds__(256) void k_rankreg(const u64* __restrict__ dense,
                                                 const u32* __restrict__ rankbuf,
                                                 const u32* __restrict__ info,
                                                 const float* __restrict__ anchors,
                                                 const float* __restrict__ deltas,
                                                 float* __restrict__ scoresel,
                                                 float* __restrict__ boxes) {
  int b = blockIdx.y;
  int i = blockIdx.x * 256 + threadIdx.x;
  int n = (int)info[20 + b];
  if (i >= n) return;
  u64 mykey = dense[(size_t)b * CAP + i];
  u32 rank = rankbuf[(size_t)b * CAP + i];
  if ((u32)mykey == 0u || rank >= PRE) return;
  u32 key = (u32)(mykey >> 32);
  u32 e = ~((u32)mykey);
  u32 u = (key & 0x80000000u) ? (key ^ 0x80000000u) : ~key;
  scoresel[b * PRE + rank] = __uint_as_float(u);
  const float* an = anchors + (size_t)e * 6;
  const float* de = deltas + ((size_t)b * ANUM + e) * 6;
  float* ob = boxes + ((size_t)b * PRE + rank) * 6;
#pragma unroll
  for (int d = 0; d < 3; ++d) {
    float lo = an[d], hi = an[3 + d];
    float dims = __fsub_rn(hi, lo);
    float ctr = __fadd_rn(lo, __fmul_rn(0.5f, dims));
    ctr = __fadd_rn(ctr, __fmul_rn(de[d], dims));
    float nd = __fmul_rn(dims, expf(de[3 + d]));
    float h = __fmul_rn(0.5f, nd);
    ob[d] = __fsub_rn(ctr, h);
    ob[3 + d] = __fadd_rn(ctr, h);
  }
}

/* ---------- 6. suppression bitmask — triangular linear grid ---------- */
__global__ void k_mask(const float* __restrict__ boxes, u64* __restrict__ masks,
                       u64* __restrict__ diag, u64* __restrict__ rownz) {
  int L = blockIdx.x, b = blockIdx.y;
  int r = (int)((sqrtf(8.0f * (float)L + 1.0f) - 1.0f) * 0.5f);
  while ((r + 1) * (r + 2) / 2 <= L) ++r;
  while (r * (r + 1) / 2 > L) --r;
  int jblk = r, iblk = L - r * (r + 1) / 2;            /* iblk <= jblk */
  int tid = threadIdx.x;                                /* 64 */
  __shared__ float cb[64][7];
  int j0 = jblk * 64;
  {
    int jj = j0 + tid; if (jj > PRE - 1) jj = PRE - 1;
    const float* src = boxes + ((size_t)b * PRE + jj) * 6;
#pragma unroll
    for (int d = 0; d < 6; ++d) cb[tid][d] = src[d];
    float dx = fmaxf(__fsub_rn(cb[tid][3], cb[tid][0]), 0.0f);
    float dy = fmaxf(__fsub_rn(cb[tid][4], cb[tid][1]), 0.0f);
    float dz = fmaxf(__fsub_rn(cb[tid][5], cb[tid][2]), 0.0f);
    cb[tid][6] = __fmul_rn(__fmul_rn(dx, dy), dz);
  }
  __syncthreads();
  int i = iblk * 64 + tid;
  if (i >= PRE) return;
  u64 bits = 0;
  if (j0 + 63 > i) {
    const float* rb = boxes + ((size_t)b * PRE + i) * 6;
    float l0 = rb[0], l1 = rb[1], l2 = rb[2], h0 = rb[3], h1 = rb[4], h2 = rb[5];
    float dx = fmaxf(__fsub_rn(h0, l0), 0.0f);
    float dy = fmaxf(__fsub_rn(h1, l1), 0.0f);
    float dz = fmaxf(__fsub_rn(h2, l2), 0.0f);
    float vi = __fmul_rn(__fmul_rn(dx, dy), dz);
    for (int c = 0; c < 64; ++c) {
      int j = j0 + c;
      if (j > i && j < PRE) {
        float ix = fmaxf(__fsub_rn(fminf(h0, cb[c][3]), fmaxf(l0, cb[c][0])), 0.0f);
        float iy = fmaxf(__fsub_rn(fminf(h1, cb[c][4]), fmaxf(l1, cb[c][1])), 0.0f);
        float iz = fmaxf(__fsub_rn(fminf(h2, cb[c][5]), fmaxf(l2, cb[c][2])), 0.0f);
        float iv = __fmul_rn(__fmul_rn(ix, iy), iz);
        float un = fmaxf(__fsub_rn(__fadd_rn(vi, cb[c][6]), iv), 1e-8f);
        float iou = __fdiv_rn(iv, un);
        if (iou > 0.7f) bits |= (1ull << c);
      }
    }
  }
  masks[((size_t)b * PRE + i) * MROW + jblk] = bits;
  if (iblk == jblk) diag[((size_t)b * NW + jblk) * 64 + tid] = bits;
  u64 bal = __ballot(bits != 0ull);
  if (tid == 0 && bal) atomicOr(&rownz[b * NW + iblk], bal);
}

/* ---------- 7. fused scan + output: wave 0 scans (kept -> LDS), 4 waves emit ---------- */
__global__ __launch_bounds__(256) void k_scanout(const u64* __restrict__ masks,
                                                 const u64* __restrict__ diag,
                                                 const u64* __restrict__ rownz,
                                                 const float* __restrict__ boxes,
                                                 const float* __restrict__ scoresel,
                                                 float* __restrict__ out) {
  __shared__ u32 keptL[MAXOUT];
  __shared__ u32 cntL;
  int b = blockIdx.x;
  int tid = threadIdx.x;

  if (tid < 64) {                                      /* wave 0: sequential scan */
    int lane = tid;
    const u64* Mb = masks + (size_t)b * PRE * MROW;
    const u64* Db = diag + (size_t)b * NW * 64;
    const u64* Nb = rownz + b * NW;
    int wl = lane < NW ? lane : NW - 1;
    u64 rem = 0;
    int cnt = 0;

    u64 dcur = Db[lane];
    u64 nzcur = Nb[0];

    for (int c = 0; c < NW; ++c) {
      int base = c * 64;
      int nrow = (base + 64 <= PRE) ? 64 : (PRE - base);

      u64 dn = (c + 1 < NW) ? Db[(size_t)(c + 1) * 64 + lane] : 0ull;
      u64 nzn = (c + 1 < NW) ? Nb[c + 1] : 0ull;

      u32 rlo = __shfl((u32)rem, c);
      u32 rhi = __shfl((u32)(rem >> 32), c);
      u64 pending = ~(((u64)rhi << 32) | (u64)rlo);
      if (nrow < 64) pending &= ((1ull << nrow) - 1ull);

      u64 Z = __ballot(dcur != 0ull);
      u64 chain = pending & Z;
      while (chain) {
        int k = __builtin_ctzll(chain);
        u32 rl = (u32)__builtin_amdgcn_readlane((int)(u32)dcur, k);
        u32 rh = (u32)__builtin_amdgcn_readlane((int)(u32)(dcur >> 32), k);
        u64 rw = ((u64)rh << 32) | (u64)rl;
        pending &= ~rw;
        chain &= pending;
        chain &= ~(1ull << k);
      }
      u64 keep = pending;

      u64 ltmask = (lane == 0) ? 0ull : (~0ull >> (64 - lane));
      int pos = __popcll(keep & ltmask);
      int slot = cnt + pos;
      if (((keep >> lane) & 1ull) && slot < MAXOUT) keptL[slot] = (u32)(base + lane);
      cnt += (int)__popcll(keep);

      if (cnt >= MAXOUT) break;

      u64 nz = keep & nzcur;
      while (nz) {
        int rks[8]; int m = 0; int rr = base;
#pragma unroll
        for (int s = 0; s < 8; ++s) {
          if (nz) { rr = base + __builtin_ctzll(nz); nz &= nz - 1; ++m; }
          rks[s] = rr;
        }
        u64 v[8];
#pragma unroll
        for (int s = 0; s < 8; ++s) v[s] = Mb[(size_t)rks[s] * MROW + wl];
        u64 acc = 0;
#pragma unroll
        for (int s = 0; s < 8; ++s) acc |= (s < m) ? v[s] : 0ull;
        rem |= acc;
      }

      dcur = dn;
      nzcur = nzn;
    }
    if (lane == 0) cntL = (u32)cnt;
  }
  __syncthreads();                                     /* keptL + cntL visible to all */

  /* ---- output assembly: all 4 waves, 4 iterations each ---- */
  int cc = (int)cntL; if (cc > MAXOUT) cc = MAXOUT;
  for (int k = tid; k < MAXOUT; k += 256) {
    float pr[6] = {0.f, 0.f, 0.f, 0.f, 0.f, 0.f};
    float s = 0.f, vfl = 0.f;
    if (k < cc) {
      u32 i = keptL[k];
      const float* bx = boxes + ((size_t)b * PRE + i) * 6;
#pragma unroll
      for (int d = 0; d < 6; ++d) pr[d] = bx[d];
      s = scoresel[b * PRE + i];
      vfl = 1.f;
    }
    float* pp = out + ((size_t)(b * MAXOUT + k)) * 6;
#pragma unroll
    for (int d = 0; d < 6; ++d) pp[d] = pr[d];
    out[BATCH * MAXOUT * 6 + b * MAXOUT + k] = s;
    out[BATCH * MAXOUT * 7 + b * MAXOUT + k] = (float)b;
    out[BATCH * MAXOUT * 8 + b * MAXOUT + k] = vfl;
  }
}

extern "C" void kernel_launch(void* const* d_in, const int* in_sizes, int n_in,
                              void* d_out, int out_size, void* d_ws, size_t ws_size,
                              hipStream_t stream) {
  const float* anchors = (const float*)d_in[0];
  const float* scores  = (const float*)d_in[1];
  const float* deltas  = (const float*)d_in[2];
  float* out = (float*)d_out;

  char* w = (char*)d_ws;
  u32* part    = (u32*)(w + OFF_PART);
  u64* cand    = (u64*)(w + OFF_CAND);
  u64* diag    = (u64*)(w + OFF_DIAG);
  u64* dense   = (u64*)(w + OFF_DENSE);
  u32* rankbuf = (u32*)(w + OFF_RANKB);
  u32* info    = (u32*)(w + OFF_INFO);
  u64* rownz   = (u64*)(w + OFF_ROWNZ);
  u32* bcnt    = (u32*)(w + OFF_BCNT);
  float* scoresel = (float*)(w + OFF_SCORE);
  float* boxes = (float*)(w + OFF_BOXES);
  u64* masks   = (u64*)(w + OFF_MASKS);

  k_h12<<<BATCH * NSUB, 256, 0, stream>>>(scores, part, (u32*)(w + OFF_ROWNZ));
  k_sel12<<<BATCH, 256, 0, stream>>>(part, info);
  k_compact<<<BATCH * ANUM / 4 / 256, 256, 0, stream>>>((const float4*)scores, info, bcnt, cand);
  k_gather<<<BATCH, 1024, 0, stream>>>(cand, bcnt, dense, rankbuf, info);
  k_rank_part<<<dim3(CAP / 256, NSPLIT, BATCH), 256, 0, stream>>>(dense, info, rankbuf);
  k_rankreg<<<dim3(CAP / 256, BATCH), 256, 0, stream>>>(dense, rankbuf, info, anchors, deltas,
                                                        scoresel, boxes);
  k_mask<<<dim3(NPAIR, BATCH), 64, 0, stream>>>(boxes, masks, diag, rownz);
  k_scanout<<<BATCH, 256, 0, stream>>>(masks, diag, rownz, boxes, scoresel, out);
}